// Round 1
// baseline (171.944 us; speedup 1.0000x reference)
//
#include <hip/hip_runtime.h>
#include <hip/hip_bf16.h>

#define N_VOX 65536
#define NK 27

typedef float f32x4 __attribute__((ext_vector_type(4)));
typedef __bf16 bf16x8 __attribute__((ext_vector_type(8)));

// W[k][c][d] f32  ->  Wt[k][d][c] bf16   (transpose so B-fragments are K-contiguous)
__global__ void wconv_kernel(const float* __restrict__ W, __bf16* __restrict__ Wt,
                             int C, int D, int total) {
    int i = blockIdx.x * blockDim.x + threadIdx.x;
    if (i >= total) return;
    int d = i % D;
    int c = (i / D) % C;
    int k = i / (D * C);
    Wt[(k * D + d) * C + c] = (__bf16)W[i];
}

// One sparse-conv layer: out[n,d] = bias[d] + sum_k sum_c feat[nbr(n,k)][c] * W[k][c][d]
// Block: 256 threads (4 waves), tile = 128 rows x NCOLS.
// Per k: gather A-tile (invalid neighbor -> zero) into swizzled LDS, stage Wt[k], MFMA.
template <bool SRC_BF16, bool RELU, int NCOLS, bool OUT_F32>
__global__ __launch_bounds__(256) void conv_layer(
    const void* __restrict__ src,        // [N,64] f32 or bf16
    const int* __restrict__ nidx,        // [N,27], -1 = missing
    const __bf16* __restrict__ Wt,       // [27][NCOLS][64] bf16 (transposed)
    const float* __restrict__ bias,      // [NCOLS] f32
    void* __restrict__ dst)              // [N,NCOLS] bf16 or f32
{
    constexpr int MI = 2;                // wave covers 32 rows (2 x 16)
    constexpr int NI = NCOLS / 16;       // 4 for CH=64, 1 for COUT=16
    __shared__ __align__(16) char lds[128 * 128 + 64 * 128];
    char* Ab = lds;                      // A tile: 128 rows x 64 bf16 (128B), XOR-swizzled
    char* Bb = lds + 128 * 128;          // B tile: NCOLS rows x 64 bf16, XOR-swizzled

    const int tid  = threadIdx.x;
    const int lane = tid & 63;
    const int wid  = tid >> 6;           // 0..3
    const int col  = lane & 15;
    const int kgrp = lane >> 4;          // 0..3
    const int row0 = blockIdx.x * 128;

    f32x4 acc[MI][NI];
#pragma unroll
    for (int mi = 0; mi < MI; ++mi)
#pragma unroll
        for (int ni = 0; ni < NI; ++ni)
#pragma unroll
            for (int j = 0; j < 4; ++j) acc[mi][ni][j] = 0.f;

    for (int k = 0; k < NK; ++k) {
        __syncthreads();   // previous iteration's LDS reads done before overwrite
        // ---- stage A: 128 rows x 8 chunks(16B); chunk = 8 channels ----
#pragma unroll
        for (int it = 0; it < 4; ++it) {
            int idx = tid + it * 256;            // 0..1023
            int r = idx >> 3, q = idx & 7;
            int m = nidx[(row0 + r) * NK + k];
            int off = (r * 128 + q * 16) ^ ((r & 7) << 4);
            bf16x8 v;
            if (m >= 0) {
                if (SRC_BF16) {
                    v = *(const bf16x8*)((const __bf16*)src + (size_t)m * 64 + q * 8);
                } else {
                    const float* sp = (const float*)src + (size_t)m * 64 + q * 8;
                    f32x4 f0 = *(const f32x4*)sp;
                    f32x4 f1 = *(const f32x4*)(sp + 4);
#pragma unroll
                    for (int j = 0; j < 4; ++j) {
                        v[j]     = (__bf16)f0[j];
                        v[4 + j] = (__bf16)f1[j];
                    }
                }
            } else {
#pragma unroll
                for (int j = 0; j < 8; ++j) v[j] = (__bf16)0.f;
            }
            *(bf16x8*)(Ab + off) = v;
        }
        // ---- stage B: Wt[k], NCOLS rows x 8 chunks ----
        for (int idx = tid; idx < NCOLS * 8; idx += 256) {
            int r = idx >> 3, q = idx & 7;
            bf16x8 v = *(const bf16x8*)(Wt + ((size_t)k * NCOLS + r) * 64 + q * 8);
            *(bf16x8*)(Bb + ((r * 128 + q * 16) ^ ((r & 7) << 4))) = v;
        }
        __syncthreads();
        // ---- MFMA: M=32 (per wave), N=NCOLS, K=64 ----
#pragma unroll
        for (int kk = 0; kk < 2; ++kk) {
            int kbyte = kk * 64 + kgrp * 16;
            bf16x8 a[MI], b[NI];
#pragma unroll
            for (int mi = 0; mi < MI; ++mi) {
                int r = wid * 32 + mi * 16 + col;
                a[mi] = *(const bf16x8*)(Ab + ((r * 128 + kbyte) ^ ((r & 7) << 4)));
            }
#pragma unroll
            for (int ni = 0; ni < NI; ++ni) {
                int r = ni * 16 + col;
                b[ni] = *(const bf16x8*)(Bb + ((r * 128 + kbyte) ^ ((r & 7) << 4)));
            }
#pragma unroll
            for (int mi = 0; mi < MI; ++mi)
#pragma unroll
                for (int ni = 0; ni < NI; ++ni)
                    acc[mi][ni] = __builtin_amdgcn_mfma_f32_16x16x32_bf16(
                        a[mi], b[ni], acc[mi][ni], 0, 0, 0);
        }
    }

    // ---- epilogue: bias, relu, store ----
    // C/D layout (m89-verified): col = lane&15, row = (lane>>4)*4 + reg
#pragma unroll
    for (int ni = 0; ni < NI; ++ni) {
        float bv = bias[ni * 16 + col];
#pragma unroll
        for (int mi = 0; mi < MI; ++mi) {
#pragma unroll
            for (int reg = 0; reg < 4; ++reg) {
                int r = row0 + wid * 32 + mi * 16 + kgrp * 4 + reg;
                float v = acc[mi][ni][reg] + bv;
                if (RELU) v = fmaxf(v, 0.f);
                if (OUT_F32)
                    ((float*)dst)[(size_t)r * NCOLS + ni * 16 + col] = v;
                else
                    ((__bf16*)dst)[(size_t)r * NCOLS + ni * 16 + col] = (__bf16)v;
            }
        }
    }
}

extern "C" void kernel_launch(void* const* d_in, const int* in_sizes, int n_in,
                              void* d_out, int out_size, void* d_ws, size_t ws_size,
                              hipStream_t stream) {
    const float* x  = (const float*)d_in[0];
    const int* nidx = (const int*)d_in[1];
    const float* W1 = (const float*)d_in[2];
    const float* b1 = (const float*)d_in[3];
    const float* W2 = (const float*)d_in[4];
    const float* b2 = (const float*)d_in[5];
    const float* W3 = (const float*)d_in[6];
    const float* b3 = (const float*)d_in[7];

    // ws layout: h1 (8MB bf16) | h2 (8MB bf16) | Wt1 | Wt2 | Wt3  (~17.3 MB total)
    char* ws = (char*)d_ws;
    __bf16* h1  = (__bf16*)ws;
    __bf16* h2  = (__bf16*)(ws + 8388608);
    __bf16* Wt1 = (__bf16*)(ws + 16777216);
    __bf16* Wt2 = Wt1 + 27 * 64 * 64;
    __bf16* Wt3 = Wt2 + 27 * 64 * 64;

    wconv_kernel<<<(27 * 64 * 64 + 255) / 256, 256, 0, stream>>>(W1, Wt1, 64, 64, 27 * 64 * 64);
    wconv_kernel<<<(27 * 64 * 64 + 255) / 256, 256, 0, stream>>>(W2, Wt2, 64, 64, 27 * 64 * 64);
    wconv_kernel<<<(27 * 64 * 16 + 255) / 256, 256, 0, stream>>>(W3, Wt3, 64, 16, 27 * 64 * 16);

    dim3 grid(N_VOX / 128);
    conv_layer<false, true, 64, false><<<grid, 256, 0, stream>>>(x,  nidx, Wt1, b1, h1);
    conv_layer<true,  true, 64, false><<<grid, 256, 0, stream>>>(h1, nidx, Wt2, b2, h2);
    conv_layer<true,  false, 16, true><<<grid, 256, 0, stream>>>(h2, nidx, Wt3, b3, d_out);
}

// Round 2
// 84.170 us; speedup vs baseline: 2.0428x; 2.0428x over previous
//
#include <hip/hip_runtime.h>
#include <hip/hip_bf16.h>
#include <stdint.h>

#define N_VOX 65536
#define NK 27
#define BR 64          // rows per block

typedef float f32x4 __attribute__((ext_vector_type(4)));
typedef __bf16 bf16x8 __attribute__((ext_vector_type(8)));

#define WAITVM(n) asm volatile("s_waitcnt vmcnt(" #n ")" ::: "memory")

__device__ __forceinline__ void barrier_fence() {
    asm volatile("" ::: "memory");
    __builtin_amdgcn_s_barrier();
    asm volatile("" ::: "memory");
}

// async global->LDS, 16B per lane; LDS dest = M0 + lane*16 (wave-uniform M0)
__device__ __forceinline__ void gll16(const void* src, uint32_t lds_addr) {
    asm volatile("s_mov_b32 m0, %0\n\t"
                 "global_load_lds_dwordx4 %1, off"
                 :: "s"(lds_addr), "v"(src)
                 : "memory");
}

// x f32 -> bf16, 8 elems/thread
__global__ void cvt_kernel(const float* __restrict__ x, __bf16* __restrict__ xb, int total8) {
    int i = blockIdx.x * blockDim.x + threadIdx.x;
    if (i >= total8) return;
    const f32x4* xp = (const f32x4*)x;
    f32x4 f0 = xp[i * 2], f1 = xp[i * 2 + 1];
    bf16x8 v;
#pragma unroll
    for (int j = 0; j < 4; ++j) { v[j] = (__bf16)f0[j]; v[4 + j] = (__bf16)f1[j]; }
    ((bf16x8*)xb)[i] = v;
}

// W[k][c][d] f32 -> Wt pre-swizzled bf16 so a LINEAR 1KB-per-wave global_load_lds
// produces the XOR-swizzled LDS image directly (rule: inverse-swz source + swz read).
__global__ void wconv_kernel(const float* __restrict__ W, __bf16* __restrict__ Wt,
                             int Dc, int total) {
    int i = blockIdx.x * blockDim.x + threadIdx.x;
    if (i >= total) return;
    int d = i % Dc;                 // output channel = B row
    int c = (i / Dc) % 64;          // input channel  = B col (K)
    int k = i / (Dc * 64);
    int off = ((d * 128 + ((c >> 3) << 4)) ^ ((d & 7) << 4)) + (c & 7) * 2;
    *(__bf16*)((char*)Wt + (size_t)k * Dc * 128 + off) = (__bf16)W[i];
}

// One layer: out[n,:] = bias + sum_k feat[nbr(n,k)] @ W[k]   (invalid nbr -> 0)
// 256 thr / 4 waves, BR=64 rows, double-buffered LDS, counted-vmcnt pipeline.
template <int NCOLS, bool RELU, bool OUT_F32>
__global__ __launch_bounds__(256, 4) void conv_layer(
    const __bf16* __restrict__ feat,      // [N,64] bf16
    const int* __restrict__ nidx,         // [N,27]
    const __bf16* __restrict__ Wt,        // [27][NCOLS*64] pre-swizzled bf16
    const float* __restrict__ bias,       // [NCOLS]
    void* __restrict__ dst,               // [N,NCOLS]
    const __bf16* __restrict__ zp)        // 256B zero page
{
    constexpr int NI = NCOLS / 16;
    constexpr int BSZ = NCOLS * 128;      // B tile bytes
    constexpr int BOFF = 2 * BR * 128;    // 16384: A double buffer
    constexpr int SNOFF = BOFF + 2 * BSZ;
    __shared__ __align__(16) char lds[SNOFF + BR * NK * 4];

    const int tid = threadIdx.x;
    const int lane = tid & 63;
    const int wid = tid >> 6;
    const int col = lane & 15;
    const int kgrp = lane >> 4;
    const int row0 = blockIdx.x * BR;

    // ---- preload nidx slab (transposed: snid[k*BR + r]) ----
    int* snid = (int*)(lds + SNOFF);
    const int* gnid = nidx + (size_t)row0 * NK;
    for (int i = tid; i < BR * NK; i += 256) {
        int r = i / NK;
        int kk = i - r * NK;
        snid[kk * BR + r] = gnid[i];
    }
    __syncthreads();

    const uint32_t ldsbase = (uint32_t)(uintptr_t)(&lds[0]);
    const int uw = __builtin_amdgcn_readfirstlane(wid);

    // per-lane A gather geometry: lane covers linear LDS offset o -> (row, swz'd chunk)
    int rA[2], qA[2];
#pragma unroll
    for (int j = 0; j < 2; ++j) {
        int o = (wid * 2 + j) * 1024 + lane * 16;
        rA[j] = o >> 7;                       // row in tile
        qA[j] = ((o >> 4) & 7) ^ (rA[j] & 7); // inverse-swizzled source chunk
    }

    auto issue = [&](int k, int buf) {
#pragma unroll
        for (int j = 0; j < 2; ++j) {
            int m = snid[k * BR + rA[j]];
            const __bf16* src = (m >= 0) ? (feat + (size_t)m * 64 + qA[j] * 8) : zp;
            uint32_t la = ldsbase + buf * (BR * 128) + (wid * 2 + j) * 1024;
            gll16(src, (uint32_t)__builtin_amdgcn_readfirstlane((int)la));
        }
        if (NCOLS == 64) {
#pragma unroll
            for (int j = 0; j < 2; ++j) {
                int jb = wid * 2 + j;
                const __bf16* src = Wt + (size_t)k * (NCOLS * 64) + jb * 512 + lane * 8;
                uint32_t la = ldsbase + BOFF + buf * BSZ + jb * 1024;
                gll16(src, (uint32_t)__builtin_amdgcn_readfirstlane((int)la));
            }
        } else {
            if (uw < 2) {
                const __bf16* src = Wt + (size_t)k * (NCOLS * 64) + wid * 512 + lane * 8;
                uint32_t la = ldsbase + BOFF + buf * BSZ + wid * 1024;
                gll16(src, (uint32_t)__builtin_amdgcn_readfirstlane((int)la));
            }
        }
    };

    f32x4 acc[NI];
#pragma unroll
    for (int ni = 0; ni < NI; ++ni)
#pragma unroll
        for (int j = 0; j < 4; ++j) acc[ni][j] = 0.f;

    issue(0, 0);

    for (int k = 0; k < NK; ++k) {
        const int cur = k & 1;
        barrier_fence();                    // all reads of buf[cur^1] retired
        if (k + 1 < NK) {
            issue(k + 1, cur ^ 1);
            if (NCOLS == 64) { WAITVM(4); } // own k-loads done; k+1's stay in flight
            else { if (uw < 2) { WAITVM(3); } else { WAITVM(2); } }
        } else {
            WAITVM(0);
        }
        barrier_fence();                    // all waves' k-tiles landed

        const char* Ac = lds + cur * (BR * 128);
        const char* Bc = lds + BOFF + cur * BSZ;
        const int ar = wid * 16 + col;
        bf16x8 a[2];
#pragma unroll
        for (int kk = 0; kk < 2; ++kk)
            a[kk] = *(const bf16x8*)(Ac + ((ar * 128 + kk * 64 + kgrp * 16) ^ ((ar & 7) << 4)));
#pragma unroll
        for (int kk = 0; kk < 2; ++kk)
#pragma unroll
            for (int ni = 0; ni < NI; ++ni) {
                const int br = ni * 16 + col;
                bf16x8 b = *(const bf16x8*)(Bc + ((br * 128 + kk * 64 + kgrp * 16) ^ ((br & 7) << 4)));
                acc[ni] = __builtin_amdgcn_mfma_f32_16x16x32_bf16(a[kk], b, acc[ni], 0, 0, 0);
            }
    }

    // ---- epilogue: C/D layout col=lane&15, row=(lane>>4)*4+reg ----
#pragma unroll
    for (int ni = 0; ni < NI; ++ni) {
        float bv = bias[ni * 16 + col];
#pragma unroll
        for (int reg = 0; reg < 4; ++reg) {
            int r = row0 + wid * 16 + kgrp * 4 + reg;
            float v = acc[ni][reg] + bv;
            if (RELU) v = fmaxf(v, 0.f);
            if (OUT_F32) ((float*)dst)[(size_t)r * NCOLS + ni * 16 + col] = v;
            else ((__bf16*)dst)[(size_t)r * NCOLS + ni * 16 + col] = (__bf16)v;
        }
    }
}

extern "C" void kernel_launch(void* const* d_in, const int* in_sizes, int n_in,
                              void* d_out, int out_size, void* d_ws, size_t ws_size,
                              hipStream_t stream) {
    const float* x  = (const float*)d_in[0];
    const int* nidx = (const int*)d_in[1];
    const float* W1 = (const float*)d_in[2];
    const float* b1 = (const float*)d_in[3];
    const float* W2 = (const float*)d_in[4];
    const float* b2 = (const float*)d_in[5];
    const float* W3 = (const float*)d_in[6];
    const float* b3 = (const float*)d_in[7];

    // ws: buf0(8MB: xb, later h2) | buf1(8MB: h1) | Wt1 | Wt2 | Wt3 | zeropage
    char* ws = (char*)d_ws;
    __bf16* buf0 = (__bf16*)ws;
    __bf16* buf1 = (__bf16*)(ws + 8388608);
    __bf16* Wt1  = (__bf16*)(ws + 16777216);
    __bf16* Wt2  = Wt1 + 27 * 64 * 64;
    __bf16* Wt3  = Wt2 + 27 * 64 * 64;
    __bf16* zp   = Wt3 + 27 * 16 * 64;   // 256B-aligned (all sizes are multiples of 256)

    hipMemsetAsync(zp, 0, 256, stream);
    cvt_kernel<<<N_VOX * 64 / 8 / 256, 256, 0, stream>>>(x, buf0, N_VOX * 64 / 8);
    wconv_kernel<<<(27 * 64 * 64 + 255) / 256, 256, 0, stream>>>(W1, Wt1, 64, 27 * 64 * 64);
    wconv_kernel<<<(27 * 64 * 64 + 255) / 256, 256, 0, stream>>>(W2, Wt2, 64, 27 * 64 * 64);
    wconv_kernel<<<(27 * 16 * 64 + 255) / 256, 256, 0, stream>>>(W3, Wt3, 16, 27 * 16 * 64);

    dim3 grid(N_VOX / BR);
    conv_layer<64, true,  false><<<grid, 256, 0, stream>>>(buf0, nidx, Wt1, b1, buf1, zp);
    conv_layer<64, true,  false><<<grid, 256, 0, stream>>>(buf1, nidx, Wt2, b2, buf0, zp);
    conv_layer<16, false, true ><<<grid, 256, 0, stream>>>(buf0, nidx, Wt3, b3, d_out, zp);
}

// Round 3
// 73.396 us; speedup vs baseline: 2.3427x; 1.1468x over previous
//
#include <hip/hip_runtime.h>
#include <hip/hip_bf16.h>
#include <stdint.h>

#define N_VOX 65536
#define NK 27
#define BR 64          // rows per block

typedef float f32x4 __attribute__((ext_vector_type(4)));
typedef __bf16 bf16x8 __attribute__((ext_vector_type(8)));

#define WAITVM(n) asm volatile("s_waitcnt vmcnt(" #n ")" ::: "memory")

__device__ __forceinline__ void barrier_fence() {
    asm volatile("" ::: "memory");
    __builtin_amdgcn_s_barrier();
    asm volatile("" ::: "memory");
}

// async global->LDS, 16B per lane; LDS dest = M0 + lane*16 (wave-uniform M0)
__device__ __forceinline__ void gll16(const void* src, uint32_t lds_addr) {
    asm volatile("s_mov_b32 m0, %0\n\t"
                 "global_load_lds_dwordx4 %1, off"
                 :: "s"(lds_addr), "v"(src)
                 : "memory");
}

// W[k][c][d] f32 -> Wt pre-swizzled bf16 so a LINEAR 1KB-per-wave global_load_lds
// produces the XOR-swizzled LDS image directly (inverse-swz source + swz read).
__device__ __forceinline__ void wconv_elem(const float* __restrict__ W,
                                           __bf16* __restrict__ Wt, int Dc, int i) {
    int d = i % Dc;                 // output channel = B row
    int c = (i / Dc) % 64;          // input channel  = B col (K)
    int k = i / (Dc * 64);
    int off = ((d * 128 + ((c >> 3) << 4)) ^ ((d & 7) << 4)) + (c & 7) * 2;
    *(__bf16*)((char*)Wt + (size_t)k * Dc * 128 + off) = (__bf16)W[i];
}

// Fused prep: x f32->bf16 (2048 blocks) | W1 (432) | W2 (432) | W3 (108) | zero page (1)
#define PREP_CVT   2048
#define PREP_W1    432
#define PREP_W2    432
#define PREP_W3    108
#define PREP_GRID  (PREP_CVT + PREP_W1 + PREP_W2 + PREP_W3 + 1)
__global__ __launch_bounds__(256) void prep_kernel(
    const float* __restrict__ x,
    const float* __restrict__ W1, const float* __restrict__ W2, const float* __restrict__ W3,
    __bf16* __restrict__ xb, __bf16* __restrict__ Wt1, __bf16* __restrict__ Wt2,
    __bf16* __restrict__ Wt3, float* __restrict__ zp)
{
    const int b = blockIdx.x, tid = threadIdx.x;
    if (b < PREP_CVT) {
        int i = b * 256 + tid;                      // 8 elems/thread, exactly covers N*64
        const f32x4* xp = (const f32x4*)x;
        f32x4 f0 = xp[i * 2], f1 = xp[i * 2 + 1];
        bf16x8 v;
#pragma unroll
        for (int j = 0; j < 4; ++j) { v[j] = (__bf16)f0[j]; v[4 + j] = (__bf16)f1[j]; }
        ((bf16x8*)xb)[i] = v;
    } else if (b < PREP_CVT + PREP_W1) {
        wconv_elem(W1, Wt1, 64, (b - PREP_CVT) * 256 + tid);
    } else if (b < PREP_CVT + PREP_W1 + PREP_W2) {
        wconv_elem(W2, Wt2, 64, (b - PREP_CVT - PREP_W1) * 256 + tid);
    } else if (b < PREP_CVT + PREP_W1 + PREP_W2 + PREP_W3) {
        wconv_elem(W3, Wt3, 16, (b - PREP_CVT - PREP_W1 - PREP_W2) * 256 + tid);
    } else {
        if (tid < 16) ((f32x4*)zp)[tid] = (f32x4){0.f, 0.f, 0.f, 0.f};  // 256B zero page
    }
}

// One layer: out[n,:] = bias + sum_k feat[nbr(n,k)] @ W[k]   (invalid nbr -> 0)
// 256 thr / 4 waves, BR=64 rows, double-buffered LDS, counted-vmcnt pipeline.
template <int NCOLS, bool RELU, bool OUT_F32>
__global__ __launch_bounds__(256, 4) void conv_layer(
    const __bf16* __restrict__ feat,      // [N,64] bf16
    const int* __restrict__ nidx,         // [N,27]
    const __bf16* __restrict__ Wt,        // [27][NCOLS*64] pre-swizzled bf16
    const float* __restrict__ bias,       // [NCOLS]
    void* __restrict__ dst,               // [N,NCOLS]
    const __bf16* __restrict__ zp)        // 256B zero page
{
    constexpr int NI = NCOLS / 16;
    constexpr int BSZ = NCOLS * 128;      // B tile bytes
    constexpr int BOFF = 2 * BR * 128;    // A double buffer
    constexpr int SNOFF = BOFF + 2 * BSZ;
    __shared__ __align__(16) char lds[SNOFF + BR * NK * 4];

    const int tid = threadIdx.x;
    const int lane = tid & 63;
    const int wid = tid >> 6;
    const int col = lane & 15;
    const int kgrp = lane >> 4;
    const int row0 = blockIdx.x * BR;

    // ---- preload nidx slab (transposed: snid[k*BR + r]) ----
    int* snid = (int*)(lds + SNOFF);
    const int* gnid = nidx + (size_t)row0 * NK;
    for (int i = tid; i < BR * NK; i += 256) {
        int r = i / NK;
        int kk = i - r * NK;
        snid[kk * BR + r] = gnid[i];
    }
    __syncthreads();

    const uint32_t ldsbase = (uint32_t)(uintptr_t)(&lds[0]);
    const int uw = __builtin_amdgcn_readfirstlane(wid);

    // per-lane A gather geometry: lane covers linear LDS offset o -> (row, swz'd chunk)
    int rA[2], qA[2];
#pragma unroll
    for (int j = 0; j < 2; ++j) {
        int o = (wid * 2 + j) * 1024 + lane * 16;
        rA[j] = o >> 7;                       // row in tile
        qA[j] = ((o >> 4) & 7) ^ (rA[j] & 7); // inverse-swizzled source chunk
    }

    auto issue = [&](int k, int buf) {
#pragma unroll
        for (int j = 0; j < 2; ++j) {
            int m = snid[k * BR + rA[j]];
            const __bf16* src = (m >= 0) ? (feat + (size_t)m * 64 + qA[j] * 8) : zp;
            uint32_t la = ldsbase + buf * (BR * 128) + (wid * 2 + j) * 1024;
            gll16(src, (uint32_t)__builtin_amdgcn_readfirstlane((int)la));
        }
        if (NCOLS == 64) {
#pragma unroll
            for (int j = 0; j < 2; ++j) {
                int jb = wid * 2 + j;
                const __bf16* src = Wt + (size_t)k * (NCOLS * 64) + jb * 512 + lane * 8;
                uint32_t la = ldsbase + BOFF + buf * BSZ + jb * 1024;
                gll16(src, (uint32_t)__builtin_amdgcn_readfirstlane((int)la));
            }
        } else {
            if (uw < 2) {
                const __bf16* src = Wt + (size_t)k * (NCOLS * 64) + wid * 512 + lane * 8;
                uint32_t la = ldsbase + BOFF + buf * BSZ + wid * 1024;
                gll16(src, (uint32_t)__builtin_amdgcn_readfirstlane((int)la));
            }
        }
    };

    f32x4 acc[NI];
#pragma unroll
    for (int ni = 0; ni < NI; ++ni)
#pragma unroll
        for (int j = 0; j < 4; ++j) acc[ni][j] = 0.f;

    issue(0, 0);

    for (int k = 0; k < NK; ++k) {
        const int cur = k & 1;
        barrier_fence();                    // all reads of buf[cur^1] retired
        if (k + 1 < NK) {
            issue(k + 1, cur ^ 1);
            if (NCOLS == 64) { WAITVM(4); } // own k-loads done; k+1's stay in flight
            else { if (uw < 2) { WAITVM(3); } else { WAITVM(2); } }
        } else {
            WAITVM(0);
        }
        barrier_fence();                    // all waves' k-tiles landed

        const char* Ac = lds + cur * (BR * 128);
        const char* Bc = lds + BOFF + cur * BSZ;
        const int ar = wid * 16 + col;
        bf16x8 a[2];
#pragma unroll
        for (int kk = 0; kk < 2; ++kk)
            a[kk] = *(const bf16x8*)(Ac + ((ar * 128 + kk * 64 + kgrp * 16) ^ ((ar & 7) << 4)));
#pragma unroll
        for (int kk = 0; kk < 2; ++kk)
#pragma unroll
            for (int ni = 0; ni < NI; ++ni) {
                const int br = ni * 16 + col;
                bf16x8 b = *(const bf16x8*)(Bc + ((br * 128 + kk * 64 + kgrp * 16) ^ ((br & 7) << 4)));
                acc[ni] = __builtin_amdgcn_mfma_f32_16x16x32_bf16(a[kk], b, acc[ni], 0, 0, 0);
            }
    }

    // ---- epilogue: C/D layout col=lane&15, row=(lane>>4)*4+reg ----
#pragma unroll
    for (int ni = 0; ni < NI; ++ni) {
        float bv = bias[ni * 16 + col];
#pragma unroll
        for (int reg = 0; reg < 4; ++reg) {
            int r = row0 + wid * 16 + kgrp * 4 + reg;
            float v = acc[ni][reg] + bv;
            if (RELU) v = fmaxf(v, 0.f);
            if (OUT_F32) ((float*)dst)[(size_t)r * NCOLS + ni * 16 + col] = v;
            else ((__bf16*)dst)[(size_t)r * NCOLS + ni * 16 + col] = (__bf16)v;
        }
    }
}

extern "C" void kernel_launch(void* const* d_in, const int* in_sizes, int n_in,
                              void* d_out, int out_size, void* d_ws, size_t ws_size,
                              hipStream_t stream) {
    const float* x  = (const float*)d_in[0];
    const int* nidx = (const int*)d_in[1];
    const float* W1 = (const float*)d_in[2];
    const float* b1 = (const float*)d_in[3];
    const float* W2 = (const float*)d_in[4];
    const float* b2 = (const float*)d_in[5];
    const float* W3 = (const float*)d_in[6];
    const float* b3 = (const float*)d_in[7];

    // ws: buf0(8MB: xb, later h2) | buf1(8MB: h1) | Wt1 | Wt2 | Wt3 | zeropage
    char* ws = (char*)d_ws;
    __bf16* buf0 = (__bf16*)ws;
    __bf16* buf1 = (__bf16*)(ws + 8388608);
    __bf16* Wt1  = (__bf16*)(ws + 16777216);
    __bf16* Wt2  = Wt1 + 27 * 64 * 64;
    __bf16* Wt3  = Wt2 + 27 * 64 * 64;
    __bf16* zp   = Wt3 + 27 * 16 * 64;   // 256B-aligned

    prep_kernel<<<PREP_GRID, 256, 0, stream>>>(x, W1, W2, W3, buf0, Wt1, Wt2, Wt3, (float*)zp);

    dim3 grid(N_VOX / BR);
    conv_layer<64, true,  false><<<grid, 256, 0, stream>>>(buf0, nidx, Wt1, b1, buf1, zp);
    conv_layer<64, true,  false><<<grid, 256, 0, stream>>>(buf1, nidx, Wt2, b2, buf0, zp);
    conv_layer<16, false, true ><<<grid, 256, 0, stream>>>(buf0, nidx, Wt3, b3, d_out, zp);
}